// Round 5
// baseline (247.219 us; speedup 1.0000x reference)
//
#include <hip/hip_runtime.h>

// Pink-noise 6-pole IIR — warmup-tile parallel, ONE kernel, zero inter-block deps.
//
// Key fact: the slowest pole is 0.99886, so A^8192 = 8.7e-5 — the filter state
// forgets its history in a few thousand samples. Each block therefore scans
// 16384 samples starting from zero (8192 warmup + 8192 output tile) and writes
// only the upper half. Incoming-state truncation error <= ~6e-5 in the output
// (existing absmax 7.8e-3); tile 0 of each channel is EXACT (zero prefix =
// true zero init).
//
// Why this shape: round 1 showed cross-block flag sync costs 100s of µs
// (non-coherent XCD L2s); round 4 showed one block/CU (256 blocks) is
// parallelism-starved (hbm 33%, occupancy 18%, 55 µs). 2048 independent
// blocks with 2 co-resident per CU (LDS 64.2 KB, VGPR<=128 via
// __launch_bounds__(512,4)) overlap load and compute phases across blocks.

constexpr int kL = 65536;               // samples per channel
constexpr int kThr = 512;               // threads per block = 8 waves
constexpr int kWaves = kThr / 64;       // 8
constexpr int kT = 8192;                // output tile per block
constexpr int kW = 8192;                // warmup samples (A^8192 = 8.7e-5)
constexpr int kSpan = kT + kW;          // 16384 samples scanned per block
constexpr int kPT = kSpan / kThr;       // 32 samples per thread
constexpr int kLd = kSpan / 4 / kThr;   // 8 float4 loads per thread
constexpr int kSt = kT / 4 / kThr;      // 4 float4 stores per thread
constexpr int kTilesPerCh = kL / kT;    // 8

// XOR swizzle: bank-balances both the kPT-strided (32/thread) and the linear
// float4 access patterns; bijective; keeps float4 groups (bits 0-1) intact.
__device__ __forceinline__ int swz(int i) {
    return i ^ (((i >> 5) & 7) << 2);
}

__global__ __launch_bounds__(kThr, 4) void pink_tile(
    const float* __restrict__ white, float* __restrict__ pink)
{
    constexpr float A[6] = {0.99886f, 0.99332f, 0.969f, 0.8665f, 0.55f, -0.7616f};
    constexpr float C[6] = {0.0555179f, 0.0750759f, 0.153852f, 0.3104856f, 0.5329522f, -0.016898f};
    constexpr float B6G = 0.115926f, DIRECT = 0.5362f, OUTG = 0.11f;

    __shared__ __align__(16) float buf[kSpan];   // 64 KiB
    __shared__ float swv[6][kWaves];

    const int tid = threadIdx.x, lane = tid & 63, wave = tid >> 6;
    const int ch = blockIdx.x / kTilesPerCh;
    const int tI = blockIdx.x % kTilesPerCh;
    const size_t outBase = (size_t)ch * kL + (size_t)tI * kT;

    // ---- Load span [outBase - kW, outBase + kT) ----
    // For tI==0 the lower half is zeros (exact: zero-state before channel).
    const float4* src4 = (const float4*)(white + outBase) - (kW / 4);
    float4 v[kLd];
    #pragma unroll
    for (int k = 0; k < kLd; ++k) {
        const int j = tid + k * kThr;
        if (tI != 0 || k >= kLd / 2) v[k] = src4[j];
        else                         v[k] = make_float4(0.f, 0.f, 0.f, 0.f);
    }
    #pragma unroll
    for (int k = 0; k < kLd; ++k)
        *(float4*)&buf[swz(4 * (tid + k * kThr))] = v[k];

    // Constants: mPT = A^32, pmL = (A^32)^lane, Mwv = (A^32)^64 = A^2048.
    // (Underflow to 0 for fast poles is numerically correct.)
    float mPT[6], pmL[6], Mwv[6];
    #pragma unroll
    for (int p = 0; p < 6; ++p) {
        float q = A[p];
        #pragma unroll
        for (int i = 0; i < 5; ++i) q *= q;          // A^32
        mPT[p] = q;
        float pm = 1.f, qq = q;
        #pragma unroll
        for (int b = 0; b < 6; ++b) { if ((lane >> b) & 1) pm *= qq; qq *= qq; }
        pmL[p] = pm;
        Mwv[p] = qq;                                  // (A^32)^64 = A^2048
    }
    __syncthreads();                 // buf visible

    float w[kPT];
    #pragma unroll
    for (int kk = 0; kk < kPT / 4; ++kk) {
        float4 x = *(const float4*)&buf[swz(kPT * tid + 4 * kk)];
        w[4*kk] = x.x; w[4*kk+1] = x.y; w[4*kk+2] = x.z; w[4*kk+3] = x.w;
    }
    const float pwl = (tid == 0) ? 0.f : buf[swz(kPT * tid - 1)];

    // Local scan from zero init.
    float e[6] = {0.f, 0.f, 0.f, 0.f, 0.f, 0.f};
    #pragma unroll
    for (int k = 0; k < kPT; ++k) {
        const float ww = w[k];
        #pragma unroll
        for (int p = 0; p < 6; ++p) e[p] = fmaf(A[p], e[p], ww * C[p]);
    }

    // Intra-wave affine scan (constant per-round multiplier).
    float mk[6];
    #pragma unroll
    for (int p = 0; p < 6; ++p) mk[p] = mPT[p];
    #pragma unroll
    for (int r = 0; r < 6; ++r) {
        const int off = 1 << r;
        float fe[6];
        #pragma unroll
        for (int p = 0; p < 6; ++p) fe[p] = __shfl_up(e[p], off);
        if (lane >= off) {
            #pragma unroll
            for (int p = 0; p < 6; ++p) e[p] = fmaf(mk[p], fe[p], e[p]);
        }
        #pragma unroll
        for (int p = 0; p < 6; ++p) mk[p] *= mk[p];
    }
    float ex[6];
    #pragma unroll
    for (int p = 0; p < 6; ++p) {
        ex[p] = __shfl_up(e[p], 1);
        if (lane == 0) ex[p] = 0.f;
    }
    if (lane == 63) {
        #pragma unroll
        for (int p = 0; p < 6; ++p) swv[p][wave] = e[p];
    }
    __syncthreads();                 // swv ready; all buf reads done

    // Per-thread incoming state: fold zero-init through previous waves,
    // then apply this lane's exclusive span.
    float b[6];
    #pragma unroll
    for (int p = 0; p < 6; ++p) {
        float X = 0.f;
        #pragma unroll
        for (int w2 = 0; w2 < kWaves; ++w2)
            if (w2 < wave) X = fmaf(Mwv[p], X, swv[p][w2]);
        b[p] = fmaf(pmL[p], X, ex[p]);
    }

    // Recompute + stage outputs: only the upper (output) half of the span.
    if (tid >= kThr / 2) {
        float b6 = B6G * pwl;
        #pragma unroll
        for (int kk = 0; kk < kPT / 4; ++kk) {
            float4 o;
            float* op = &o.x;
            #pragma unroll
            for (int j = 0; j < 4; ++j) {
                const float ww = w[4*kk + j];
                #pragma unroll
                for (int p = 0; p < 6; ++p) b[p] = fmaf(A[p], b[p], ww * C[p]);
                const float sum = ((b[0]+b[1]) + (b[2]+b[3])) + ((b[4]+b[5]) + b6);
                op[j] = fmaf(DIRECT, ww, sum) * OUTG;
                b6 = B6G * ww;
            }
            *(float4*)&buf[swz(kPT * tid + 4 * kk)] = o;   // >= kW: upper half
        }
    }
    __syncthreads();                 // outputs staged

    float4* dst4 = (float4*)(pink + outBase);
    #pragma unroll
    for (int k = 0; k < kSt; ++k)
        dst4[tid + k * kThr] =
            *(const float4*)&buf[swz(kW + 4 * (tid + k * kThr))];
}

extern "C" void kernel_launch(void* const* d_in, const int* in_sizes, int n_in,
                              void* d_out, int out_size, void* d_ws, size_t ws_size,
                              hipStream_t stream) {
    const float* white = (const float*)d_in[0];
    float* pink = (float*)d_out;
    const int nCh = in_sizes[0] / kL;                 // 256 channels
    const int nBlk = nCh * kTilesPerCh;               // 2048 blocks

    hipLaunchKernelGGL(pink_tile, dim3(nBlk), dim3(kThr), 0, stream,
                       white, pink);
}

// Round 6
// 122.878 us; speedup vs baseline: 2.0119x; 2.0119x over previous
//
#include <hip/hip_runtime.h>

// Pink-noise 6-pole IIR — warmup-tile parallel, ONE kernel, zero inter-block deps.
//
// Key fact: the slowest pole is 0.99886, so A^8192 = 8.7e-5 — the filter state
// forgets its history in a few thousand samples. Each block scans 16384
// samples starting from zero (8192 warmup + 8192 output tile) and writes only
// the upper half. Truncation error <= ~1e-5 in the output (tolerance 7.8e-3);
// tile 0 of each channel is EXACT (zero prefix = true zero init).
//
// Register discipline (rounds 2/4/5 evidence): __launch_bounds__ 2nd arg acts
// as min BLOCKS per CU on this toolchain — (512,2) caps VGPR at 128 (r4: 108,
// no spill), (512,4) caps at 64 (r5: 580 MB spill traffic). LDS 64.2 KB
// already limits residency to 2 blocks/CU, so (512,2) is the right bound.
// Additionally the white samples are NOT kept in a w[32] register array —
// both scan passes re-read them from LDS (each thread reads only its own
// chunk; pwl is captured before the recompute phase), keeping the live set
// ~90 VGPRs.

constexpr int kL = 65536;               // samples per channel
constexpr int kThr = 512;               // threads per block = 8 waves
constexpr int kWaves = kThr / 64;       // 8
constexpr int kT = 8192;                // output tile per block
constexpr int kW = 8192;                // warmup samples (A^8192 = 8.7e-5)
constexpr int kSpan = kT + kW;          // 16384 samples scanned per block
constexpr int kPT = kSpan / kThr;       // 32 samples per thread
constexpr int kLd = kSpan / 4 / kThr;   // 8 float4 loads per thread
constexpr int kSt = kT / 4 / kThr;      // 4 float4 stores per thread
constexpr int kTilesPerCh = kL / kT;    // 8

// XOR swizzle: bank-balances both the kPT-strided (32/thread) and the linear
// float4 access patterns; involution; keeps float4 groups (bits 0-1) intact.
__device__ __forceinline__ int swz(int i) {
    return i ^ (((i >> 5) & 7) << 2);
}

__global__ __launch_bounds__(kThr, 2) void pink_tile(
    const float* __restrict__ white, float* __restrict__ pink)
{
    constexpr float A[6] = {0.99886f, 0.99332f, 0.969f, 0.8665f, 0.55f, -0.7616f};
    constexpr float C[6] = {0.0555179f, 0.0750759f, 0.153852f, 0.3104856f, 0.5329522f, -0.016898f};
    constexpr float B6G = 0.115926f, DIRECT = 0.5362f, OUTG = 0.11f;

    __shared__ __align__(16) float buf[kSpan];   // 64 KiB
    __shared__ float swv[6][kWaves];

    const int tid = threadIdx.x, lane = tid & 63, wave = tid >> 6;
    const int ch = blockIdx.x / kTilesPerCh;
    const int tI = blockIdx.x % kTilesPerCh;
    const size_t outBase = (size_t)ch * kL + (size_t)tI * kT;

    // ---- Load span [outBase - kW, outBase + kT) ----
    // For tI==0 the lower half is zeros (exact: zero state before channel).
    const float4* src4 = (const float4*)(white + outBase) - (kW / 4);
    float4 v[kLd];
    #pragma unroll
    for (int k = 0; k < kLd; ++k) {
        const int j = tid + k * kThr;
        if (tI != 0 || k >= kLd / 2) v[k] = src4[j];
        else                         v[k] = make_float4(0.f, 0.f, 0.f, 0.f);
    }
    #pragma unroll
    for (int k = 0; k < kLd; ++k)
        *(float4*)&buf[swz(4 * (tid + k * kThr))] = v[k];

    // Constants: mPT = A^32, pmL = (A^32)^lane, Mwv = (A^32)^64 = A^2048.
    // (Underflow to 0 for fast poles is numerically correct.)
    float mPT[6], pmL[6], Mwv[6];
    #pragma unroll
    for (int p = 0; p < 6; ++p) {
        float q = A[p];
        #pragma unroll
        for (int i = 0; i < 5; ++i) q *= q;          // A^32
        mPT[p] = q;
        float pm = 1.f, qq = q;
        #pragma unroll
        for (int b = 0; b < 6; ++b) { if ((lane >> b) & 1) pm *= qq; qq *= qq; }
        pmL[p] = pm;
        Mwv[p] = qq;                                  // (A^32)^64 = A^2048
    }
    __syncthreads();                 // buf visible

    // Previous white sample for this thread's b6 delay line (read BEFORE the
    // recompute phase can overwrite neighbors' slots).
    const float pwl = (tid == 0) ? 0.f : buf[swz(kPT * tid - 1)];

    // Local scan from zero init — white read from LDS, not kept in registers.
    float e[6] = {0.f, 0.f, 0.f, 0.f, 0.f, 0.f};
    #pragma unroll
    for (int kk = 0; kk < kPT / 4; ++kk) {
        const float4 x = *(const float4*)&buf[swz(kPT * tid + 4 * kk)];
        const float* xp = &x.x;
        #pragma unroll
        for (int j = 0; j < 4; ++j) {
            const float ww = xp[j];
            #pragma unroll
            for (int p = 0; p < 6; ++p) e[p] = fmaf(A[p], e[p], ww * C[p]);
        }
    }

    // Intra-wave affine scan (constant per-round multiplier).
    float mk[6];
    #pragma unroll
    for (int p = 0; p < 6; ++p) mk[p] = mPT[p];
    #pragma unroll
    for (int r = 0; r < 6; ++r) {
        const int off = 1 << r;
        float fe[6];
        #pragma unroll
        for (int p = 0; p < 6; ++p) fe[p] = __shfl_up(e[p], off);
        if (lane >= off) {
            #pragma unroll
            for (int p = 0; p < 6; ++p) e[p] = fmaf(mk[p], fe[p], e[p]);
        }
        #pragma unroll
        for (int p = 0; p < 6; ++p) mk[p] *= mk[p];
    }
    float ex[6];
    #pragma unroll
    for (int p = 0; p < 6; ++p) {
        ex[p] = __shfl_up(e[p], 1);
        if (lane == 0) ex[p] = 0.f;
    }
    if (lane == 63) {
        #pragma unroll
        for (int p = 0; p < 6; ++p) swv[p][wave] = e[p];
    }
    __syncthreads();                 // swv ready

    // Per-thread incoming state: fold zero-init through previous waves,
    // then apply this lane's exclusive span.
    float b[6];
    #pragma unroll
    for (int p = 0; p < 6; ++p) {
        float X = 0.f;
        #pragma unroll
        for (int w2 = 0; w2 < kWaves; ++w2)
            if (w2 < wave) X = fmaf(Mwv[p], X, swv[p][w2]);
        b[p] = fmaf(pmL[p], X, ex[p]);
    }

    // Recompute + stage outputs: only the upper (output) half of the span.
    // Each thread re-reads its own chunk from LDS and overwrites it in place —
    // no cross-thread overlap (pwl was captured above).
    if (tid >= kThr / 2) {
        float b6 = B6G * pwl;
        #pragma unroll
        for (int kk = 0; kk < kPT / 4; ++kk) {
            const float4 x = *(const float4*)&buf[swz(kPT * tid + 4 * kk)];
            const float* xp = &x.x;
            float4 o;
            float* op = &o.x;
            #pragma unroll
            for (int j = 0; j < 4; ++j) {
                const float ww = xp[j];
                #pragma unroll
                for (int p = 0; p < 6; ++p) b[p] = fmaf(A[p], b[p], ww * C[p]);
                const float sum = ((b[0]+b[1]) + (b[2]+b[3])) + ((b[4]+b[5]) + b6);
                op[j] = fmaf(DIRECT, ww, sum) * OUTG;
                b6 = B6G * ww;
            }
            *(float4*)&buf[swz(kPT * tid + 4 * kk)] = o;   // >= kW: upper half
        }
    }
    __syncthreads();                 // outputs staged

    float4* dst4 = (float4*)(pink + outBase);
    #pragma unroll
    for (int k = 0; k < kSt; ++k)
        dst4[tid + k * kThr] =
            *(const float4*)&buf[swz(kW + 4 * (tid + k * kThr))];
}

extern "C" void kernel_launch(void* const* d_in, const int* in_sizes, int n_in,
                              void* d_out, int out_size, void* d_ws, size_t ws_size,
                              hipStream_t stream) {
    const float* white = (const float*)d_in[0];
    float* pink = (float*)d_out;
    const int nCh = in_sizes[0] / kL;                 // 256 channels
    const int nBlk = nCh * kTilesPerCh;               // 2048 blocks

    hipLaunchKernelGGL(pink_tile, dim3(nBlk), dim3(kThr), 0, stream,
                       white, pink);
}